// Round 11
// baseline (236.980 us; speedup 1.0000x reference)
//
#include <hip/hip_runtime.h>

#define NN 50000
#define NE 800000
#define DIMH 128
#define NGRAPH 64
#define NTILES 3125          // 50000 / 16
#define MLP_BLOCKS 1563      // 2 pairs/block, 1 tile per pair (3126 >= 3125)
#define NBIN 196             // dst >> 8
#define BCAP 8064            // staging capacity per bin (max load ~4.4K)
#define SL_US 800000         // ushorts per feature-slice (NN*16)
#define SL_U4 100000         // uint4 per feature-slice

typedef __attribute__((ext_vector_type(8))) short bf16x8;
typedef __attribute__((ext_vector_type(4))) float f32x4;

__device__ __forceinline__ unsigned short f2b(float f) {
  unsigned int b = __float_as_uint(f);
  unsigned int r = (b + 0x7FFFu + ((b >> 16) & 1u)) >> 16;  // RNE
  return (unsigned short)r;
}
__device__ __forceinline__ float b2f_lo(unsigned int u) { return __uint_as_float(u << 16); }
__device__ __forceinline__ float b2f_hi(unsigned int u) { return __uint_as_float(u & 0xffff0000u); }
__device__ __forceinline__ unsigned int pk2(float lo, float hi) {
  return (unsigned int)f2b(lo) | ((unsigned int)f2b(hi) << 16);
}
__device__ __forceinline__ void add8(float* a, uint4 u) {
  a[0] += b2f_lo(u.x); a[1] += b2f_hi(u.x);
  a[2] += b2f_lo(u.y); a[3] += b2f_hi(u.y);
  a[4] += b2f_lo(u.z); a[5] += b2f_hi(u.z);
  a[6] += b2f_lo(u.w); a[7] += b2f_hi(u.w);
}

// ---------------- binned compact-CSR build ----------------

__global__ __launch_bounds__(256) void bin_scatter_kernel(const int* __restrict__ src,
                                                          const int* __restrict__ dst,
                                                          int* __restrict__ gcnt,
                                                          int2* __restrict__ staging) {
  __shared__ int hist[NBIN];
  __shared__ int base[NBIN];
  int tid = threadIdx.x;
  for (int i = tid; i < NBIN; i += 256) hist[i] = 0;
  __syncthreads();
  int e0 = blockIdx.x * 2048;
  int2 ed[8];
  int bin[8], rank[8];
#pragma unroll
  for (int k = 0; k < 8; ++k) {
    int e = e0 + k * 256 + tid;
    bin[k] = 0; rank[k] = 0; ed[k] = make_int2(0, 0);
    if (e < NE) {
      ed[k].x = src[e]; ed[k].y = dst[e];
      bin[k] = ed[k].y >> 8;
      rank[k] = atomicAdd(&hist[bin[k]], 1);
    }
  }
  __syncthreads();
  for (int i = tid; i < NBIN; i += 256) base[i] = atomicAdd(&gcnt[i], hist[i]);
  __syncthreads();
#pragma unroll
  for (int k = 0; k < 8; ++k) {
    int e = e0 + k * 256 + tid;
    if (e < NE) staging[bin[k] * BCAP + base[bin[k]] + rank[k]] = ed[k];
  }
}

// one block per bin; row starts rounded to EVEN so agg's int2 index loads are
// 8B-aligned.
__global__ __launch_bounds__(256) void bin_fill_kernel(const int2* __restrict__ staging,
                                                       const int* __restrict__ gcnt,
                                                       int* __restrict__ adj,
                                                       int* __restrict__ row_ptr,
                                                       int* __restrict__ cnt,
                                                       int* __restrict__ alloc) {
  __shared__ int hdeg[256], loc[256], c2[256];
  __shared__ int sbase;
  int b = blockIdx.x;
  int tid = threadIdx.x;
  hdeg[tid] = 0; c2[tid] = 0;
  __syncthreads();
  int n = gcnt[b];
  for (int i = tid; i < n; i += 256)
    atomicAdd(&hdeg[staging[b * BCAP + i].y & 255], 1);
  __syncthreads();
  int v = hdeg[tid];
  int va = (v + 1) & ~1;  // even-aligned allocation
  loc[tid] = va;
  __syncthreads();
  for (int off = 1; off < 256; off <<= 1) {
    int t = (tid >= off) ? loc[tid - off] : 0;
    __syncthreads();
    loc[tid] += t;
    __syncthreads();
  }
  if (tid == 255) sbase = atomicAdd(alloc, loc[255]);
  __syncthreads();
  int excl = loc[tid] - va;
  int node = b * 256 + tid;
  if (node < NN) { row_ptr[node] = sbase + excl; cnt[node] = v; }
  loc[tid] = excl;
  __syncthreads();
  for (int i = tid; i < n; i += 256) {
    int2 e = staging[b * BCAP + i];
    int local = e.y & 255;
    int r = atomicAdd(&c2[local], 1);
    adj[sbase + loc[local] + r] = e.x;
  }
}

// ---------------- prep: weight transposes + v2/s2 + out init + counters ----------------

struct WPtrs { const float* w[6]; const float* b_out; const float* b2_last;
               const float* w_out; };

__global__ __launch_bounds__(256) void prep_kernel(WPtrs ptrs, unsigned short* __restrict__ wt,
                                                   float* __restrict__ out,
                                                   int* __restrict__ gcnt,
                                                   int* __restrict__ alloc,
                                                   float* __restrict__ v2,
                                                   float* __restrict__ s2) {
  int i = blockIdx.x * 256 + threadIdx.x;  // 6*16384 elems, m uniform per block
  int m = i >> 14;
  int idx = i & 16383;
  int c = idx >> 7, k = idx & 127;
  wt[m * 16384 + idx] = f2b(ptrs.w[m][k * DIMH + c]);
  if (i < NGRAPH) out[i] = ptrs.b_out[0];
  if (i < NBIN) gcnt[i] = 0;
  if (i == NBIN) *alloc = 0;
  if (i < DIMH) {  // v2[k] = sum_c W2_l2[k][c] * w_out[256+c]  (4-way ILP)
    const float* w2r = ptrs.w[5] + i * DIMH;
    const float* wo = ptrs.w_out + 2 * DIMH;
    float s0 = 0.f, s1 = 0.f, sa = 0.f, sb = 0.f;
#pragma unroll 4
    for (int cc = 0; cc < DIMH; cc += 4) {
      s0 += w2r[cc] * wo[cc];
      s1 += w2r[cc + 1] * wo[cc + 1];
      sa += w2r[cc + 2] * wo[cc + 2];
      sb += w2r[cc + 3] * wo[cc + 3];
    }
    v2[i] = (s0 + s1) + (sa + sb);
  }
  if (i == DIMH) {  // s2 = dot(b2_l2, w_out[256:])
    const float* wo = ptrs.w_out + 2 * DIMH;
    float s0 = 0.f, s1 = 0.f, sa = 0.f, sb = 0.f;
#pragma unroll 4
    for (int cc = 0; cc < DIMH; cc += 4) {
      s0 += ptrs.b2_last[cc] * wo[cc];
      s1 += ptrs.b2_last[cc + 1] * wo[cc + 1];
      sa += ptrs.b2_last[cc + 2] * wo[cc + 2];
      sb += ptrs.b2_last[cc + 3] * wo[cc + 3];
    }
    *s2 = (s0 + s1) + (sa + sb);
  }
}

// h (row-major fp32) -> sliced bf16 [slice][node][16f]
__global__ void convh_kernel(const float* __restrict__ h, uint2* __restrict__ Hs) {
  int t = blockIdx.x * 256 + threadIdx.x;  // NN*32 groups of 4 feats
  if (t >= NN * 32) return;
  int node = t >> 5;
  int q = t & 31;            // feat group: feats q*4..q*4+3
  float4 v = *(const float4*)&h[node * DIMH + q * 4];
  uint2 o;
  o.x = pk2(v.x, v.y);
  o.y = pk2(v.z, v.w);
  Hs[(q >> 2) * (SL_U4 * 2) + node * 4 + (q & 3)] = o;
}

// ---------------- aggregation: sliced, XCD-affine, deep-ILP ----------------
__global__ __launch_bounds__(256) void agg_kernel(const uint4* __restrict__ Hs,
                                                  const int* __restrict__ row_ptr,
                                                  const int* __restrict__ cnt,
                                                  const int* __restrict__ adj,
                                                  uint4* __restrict__ Zs) {
  int bid = blockIdx.x;
  int slice = bid & 7;
  int nb = bid >> 3;
  int tid = threadIdx.x;
  int node = nb * 128 + (tid >> 1);
  int l2 = tid & 1;
  if (node >= NN) return;
  const uint4* hp = Hs + slice * SL_U4;
  int start = row_ptr[node];
  int c = cnt[node];
  float a[8];
  {
    uint4 own = hp[node * 2 + l2];
    a[0] = b2f_lo(own.x); a[1] = b2f_hi(own.x);
    a[2] = b2f_lo(own.y); a[3] = b2f_hi(own.y);
    a[4] = b2f_lo(own.z); a[5] = b2f_hi(own.z);
    a[6] = b2f_lo(own.w); a[7] = b2f_hi(own.w);
  }
  int j = 0;
  for (; j + 8 <= c; j += 8) {
    int2 i01 = *(const int2*)(adj + start + j);
    int2 i23 = *(const int2*)(adj + start + j + 2);
    int2 i45 = *(const int2*)(adj + start + j + 4);
    int2 i67 = *(const int2*)(adj + start + j + 6);
    uint4 u0 = hp[i01.x * 2 + l2];
    uint4 u1 = hp[i01.y * 2 + l2];
    uint4 u2 = hp[i23.x * 2 + l2];
    uint4 u3 = hp[i23.y * 2 + l2];
    uint4 u4 = hp[i45.x * 2 + l2];
    uint4 u5 = hp[i45.y * 2 + l2];
    uint4 u6 = hp[i67.x * 2 + l2];
    uint4 u7 = hp[i67.y * 2 + l2];
    add8(a, u0); add8(a, u1); add8(a, u2); add8(a, u3);
    add8(a, u4); add8(a, u5); add8(a, u6); add8(a, u7);
  }
  for (; j + 2 <= c; j += 2) {
    int2 i01 = *(const int2*)(adj + start + j);
    uint4 u0 = hp[i01.x * 2 + l2];
    uint4 u1 = hp[i01.y * 2 + l2];
    add8(a, u0); add8(a, u1);
  }
  if (j < c) {
    int n0 = adj[start + j];
    add8(a, hp[n0 * 2 + l2]);
  }
  uint4 o;
  o.x = pk2(a[0], a[1]);
  o.y = pk2(a[2], a[3]);
  o.z = pk2(a[4], a[5]);
  o.w = pk2(a[6], a[7]);
  Zs[slice * SL_U4 + node * 2 + l2] = o;
}

// ---------------- MLP: one 16-row tile per wave-pair (high TLP) ----------------
// fb1 loaded -> GEMM1 -> fb2 loads issued (latency overlaps barrier) -> GEMM2.
// Staging fb1/fb2 keeps peak VGPR ~100 -> 4 blocks/CU (16 waves/CU) at
// __launch_bounds__(256,4). Last layer: GEMM2 collapsed into v2-dot in GEMM1
// epilogue (w_out readout only needs dot(y2, wo) = dot(relu1, W2 wo) + const).
__global__ __launch_bounds__(256, 4) void mlp_kernel(const unsigned short* __restrict__ X,
                                                     const unsigned short* __restrict__ W1t,
                                                     const float* __restrict__ b1,
                                                     const unsigned short* __restrict__ W2t,
                                                     const float* __restrict__ b2,
                                                     unsigned short* __restrict__ Y,
                                                     const int* __restrict__ gids,
                                                     const float* __restrict__ wout,
                                                     float* __restrict__ gout,
                                                     const float* __restrict__ v2,
                                                     const float* __restrict__ s2p) {
  __shared__ unsigned short y1[2][2048];  // [pair][16 rows x 128 cols bf16]
  __shared__ float s_gout[NGRAPH];
  int tid = threadIdx.x;
  if (tid < NGRAPH) s_gout[tid] = 0.f;
  bool last = (v2 != nullptr);

  int wv = tid >> 6;
  int lane = tid & 63;
  int pb = wv >> 1;
  int half = wv & 1;
  int l15 = lane & 15;
  int g = lane >> 4;
  int rtc = blockIdx.x * 2 + pb;
  bool active = rtc < NTILES;
  int rts = active ? rtc : 0;  // clamp for loads

  // sliced A-load: feats kt*32+g*8..+7 of row R -> slice 2kt+(g>>1), half (g&1)
  int asl_base = (g >> 1) * SL_US + (g & 1) * 8 + l15 * 16;
  bf16x8 a[4];
  {
    int roff = rts * 256;
#pragma unroll
    for (int kt = 0; kt < 4; ++kt)
      a[kt] = *(const bf16x8*)(X + 2 * kt * SL_US + roff + asl_base);
  }

  // stage 1 weights only (fb2 loaded after GEMM1 to cap register pressure)
  bf16x8 fb1[4][4];
  const unsigned short* w1b = W1t + (half * 64 + l15) * DIMH + g * 8;
#pragma unroll
  for (int n = 0; n < 4; ++n)
#pragma unroll
    for (int kt = 0; kt < 4; ++kt)
      fb1[n][kt] = *(const bf16x8*)(w1b + n * 16 * DIMH + kt * 32);

  float b1v[4], v2v[4];
#pragma unroll
  for (int n = 0; n < 4; ++n) {
    int col = half * 64 + n * 16 + l15;
    b1v[n] = b1[col];
    v2v[n] = last ? v2[col] : 0.f;
  }
  float s2v = last ? *s2p : 0.f;
  __syncthreads();  // s_gout zero visible

  unsigned short* buf = y1[pb];
  if (active) {
    float pr1[4] = {0.f, 0.f, 0.f, 0.f};
#pragma unroll
    for (int n = 0; n < 4; ++n) {
      f32x4 acc = (f32x4){0.f, 0.f, 0.f, 0.f};
#pragma unroll
      for (int kt = 0; kt < 4; ++kt)
        acc = __builtin_amdgcn_mfma_f32_16x16x32_bf16(a[kt], fb1[n][kt], acc, 0, 0, 0);
      int col2 = (half * 64 + n * 16 + l15) * 2;
#pragma unroll
      for (int r = 0; r < 4; ++r) {
        float f = fmaxf(acc[r] + b1v[n], 0.f);
        if (!last) {
          int row = 4 * g + r;
          buf[((row * 256 + col2) ^ (row << 4)) >> 1] = f2b(f);
        } else {
          pr1[r] += f * v2v[n];
        }
      }
    }
    if (last) {
#pragma unroll
      for (int r = 0; r < 4; ++r) {
#pragma unroll
        for (int off = 1; off < 16; off <<= 1) pr1[r] += __shfl_xor(pr1[r], off, 64);
      }
      if (l15 == 0) {
        float s2add = (half == 0) ? s2v : 0.f;  // s2 once per row
#pragma unroll
        for (int r = 0; r < 4; ++r)
          atomicAdd(&s_gout[gids[rtc * 16 + 4 * g + r]], pr1[r] + s2add);
      }
    }
  }

  if (!last) {
    // stage 2 weights: issue before the barrier so latency overlaps it
    bf16x8 fb2[4][4];
    const unsigned short* w2b = W2t + (half * 64 + l15) * DIMH + g * 8;
#pragma unroll
    for (int n = 0; n < 4; ++n)
#pragma unroll
      for (int kt = 0; kt < 4; ++kt)
        fb2[n][kt] = *(const bf16x8*)(w2b + n * 16 * DIMH + kt * 32);
    float b2v[4], wov[4];
#pragma unroll
    for (int n = 0; n < 4; ++n) {
      int col = half * 64 + n * 16 + l15;
      b2v[n] = b2[col];
      wov[n] = wout[col];
    }

    __syncthreads();  // y1 tile complete (both halves)

    if (active) {
      bf16x8 a2[4];
#pragma unroll
      for (int kt = 0; kt < 4; ++kt)
        a2[kt] = *(const bf16x8*)&buf[((l15 * 256 + kt * 64 + g * 16) ^ (l15 << 4)) >> 1];

      float pr[4] = {0.f, 0.f, 0.f, 0.f};
#pragma unroll
      for (int n = 0; n < 4; ++n) {
        f32x4 acc = (f32x4){0.f, 0.f, 0.f, 0.f};
#pragma unroll
        for (int kt = 0; kt < 4; ++kt)
          acc = __builtin_amdgcn_mfma_f32_16x16x32_bf16(a2[kt], fb2[n][kt], acc, 0, 0, 0);
        int sl = 4 * half + n;  // output col slice
#pragma unroll
        for (int r = 0; r < 4; ++r) {
          float f = acc[r] + b2v[n];
          Y[sl * SL_US + (rtc * 16 + 4 * g + r) * 16 + l15] = f2b(f);
          pr[r] += f * wov[n];
        }
      }
#pragma unroll
      for (int r = 0; r < 4; ++r) {
#pragma unroll
        for (int off = 1; off < 16; off <<= 1) pr[r] += __shfl_xor(pr[r], off, 64);
      }
      if (l15 == 0) {
#pragma unroll
        for (int r = 0; r < 4; ++r)
          atomicAdd(&s_gout[gids[rtc * 16 + 4 * g + r]], pr[r]);
      }
    }
  }

  __syncthreads();
  if (tid < NGRAPH) {
    float v = s_gout[tid];
    if (v != 0.f) atomicAdd(&gout[tid], v);
  }
}

// ---------------- launch ----------------

extern "C" void kernel_launch(void* const* d_in, const int* in_sizes, int n_in,
                              void* d_out, int out_size, void* d_ws, size_t ws_size,
                              hipStream_t stream) {
  const float* h = (const float*)d_in[0];
  const int* src = (const int*)d_in[1];
  const int* dst = (const int*)d_in[2];
  const int* gids = (const int*)d_in[3];
  const float* w_out = (const float*)d_in[16];
  const float* b_out = (const float*)d_in[17];
  float* out = (float*)d_out;

  char* base = (char*)d_ws;
  unsigned short* buf0 = (unsigned short*)(base);             // 12.8 MB (sliced io ping)
  unsigned short* buf1 = (unsigned short*)(base + 12800000);  // 12.8 MB (sliced io pong)
  int2* staging = (int2*)(base + 25600000);                   // 12,644,352 B
  int* adj = (int*)(base + 38400000);                         // 3,400,000 B (even-padded)
  int* row_ptr = (int*)(base + 41800064);                     // 200,000 B
  int* cnt = (int*)(base + 42000128);                         // 200,000 B
  int* gcnt = (int*)(base + 42200192);                        // 784 B
  int* alloc = (int*)(base + 42201024);                       // 4 B
  unsigned short* wt = (unsigned short*)(base + 42201088);    // 196,608 B
  float* v2 = (float*)(base + 42397696);                      // 512 B
  float* s2 = (float*)(base + 42398208);                      // 4 B
  unsigned short* Zs = (unsigned short*)(base + 42400000);    // 12.8 MB

  WPtrs ptrs;
  for (int l = 0; l < 3; ++l) {
    ptrs.w[2 * l] = (const float*)d_in[4 + l * 4];
    ptrs.w[2 * l + 1] = (const float*)d_in[6 + l * 4];
  }
  ptrs.b_out = b_out;
  ptrs.b2_last = (const float*)d_in[15];
  ptrs.w_out = w_out;

  prep_kernel<<<384, 256, 0, stream>>>(ptrs, wt, out, gcnt, alloc, v2, s2);
  bin_scatter_kernel<<<(NE + 2047) / 2048, 256, 0, stream>>>(src, dst, gcnt, staging);
  bin_fill_kernel<<<NBIN, 256, 0, stream>>>(staging, gcnt, adj, row_ptr, cnt, alloc);
  convh_kernel<<<(NN * 32 + 255) / 256, 256, 0, stream>>>(h, (uint2*)buf0);

  int agg_blocks = 391 * 8;  // ceil(50000/128) node-blocks x 8 slices (bid&7 = slice)

  for (int l = 0; l < 3; ++l) {
    const float* b1 = (const float*)d_in[5 + l * 4];
    const float* b2 = (const float*)d_in[7 + l * 4];
    const unsigned short* Hl = (l & 1) ? buf1 : buf0;
    unsigned short* Yl = (l & 1) ? buf0 : buf1;
    int lastl = (l == 2);
    agg_kernel<<<agg_blocks, 256, 0, stream>>>((const uint4*)Hl, row_ptr, cnt, adj,
                                               (uint4*)Zs);
    mlp_kernel<<<MLP_BLOCKS, 256, 0, stream>>>(Zs, wt + (2 * l) * 16384, b1,
                                               wt + (2 * l + 1) * 16384, b2,
                                               lastl ? nullptr : Yl,
                                               gids, w_out + l * DIMH, out,
                                               lastl ? v2 : nullptr,
                                               lastl ? s2 : nullptr);
  }
}

// Round 12
// 215.246 us; speedup vs baseline: 1.1010x; 1.1010x over previous
//
#include <hip/hip_runtime.h>

#define NN 50000
#define NE 800000
#define DIMH 128
#define NGRAPH 64
#define NTILES 3125          // 50000 / 16
#define PAIRS 1024           // wave-pairs in mlp_mid grid
#define MLP_BLOCKS 512       // 2 pairs/block
#define MLP_ITERS 4          // ceil(3125/1024)
#define NBIN 196             // dst >> 8
#define BCAP 8064            // staging capacity per bin (max load ~4.4K)
#define SL_US 800000         // ushorts per feature-slice (NN*16)
#define SL_U4 100000         // uint4 per feature-slice

typedef __attribute__((ext_vector_type(8))) short bf16x8;
typedef __attribute__((ext_vector_type(4))) float f32x4;

__device__ __forceinline__ unsigned short f2b(float f) {
  unsigned int b = __float_as_uint(f);
  unsigned int r = (b + 0x7FFFu + ((b >> 16) & 1u)) >> 16;  // RNE
  return (unsigned short)r;
}
__device__ __forceinline__ float b2f_lo(unsigned int u) { return __uint_as_float(u << 16); }
__device__ __forceinline__ float b2f_hi(unsigned int u) { return __uint_as_float(u & 0xffff0000u); }
__device__ __forceinline__ unsigned int pk2(float lo, float hi) {
  return (unsigned int)f2b(lo) | ((unsigned int)f2b(hi) << 16);
}
__device__ __forceinline__ void add8(float* a, uint4 u) {
  a[0] += b2f_lo(u.x); a[1] += b2f_hi(u.x);
  a[2] += b2f_lo(u.y); a[3] += b2f_hi(u.y);
  a[4] += b2f_lo(u.z); a[5] += b2f_hi(u.z);
  a[6] += b2f_lo(u.w); a[7] += b2f_hi(u.w);
}

// ---------------- binned compact-CSR build ----------------

__global__ __launch_bounds__(256) void bin_scatter_kernel(const int* __restrict__ src,
                                                          const int* __restrict__ dst,
                                                          int* __restrict__ gcnt,
                                                          int2* __restrict__ staging) {
  __shared__ int hist[NBIN];
  __shared__ int base[NBIN];
  int tid = threadIdx.x;
  for (int i = tid; i < NBIN; i += 256) hist[i] = 0;
  __syncthreads();
  int e0 = blockIdx.x * 2048;
  int2 ed[8];
  int bin[8], rank[8];
#pragma unroll
  for (int k = 0; k < 8; ++k) {
    int e = e0 + k * 256 + tid;
    bin[k] = 0; rank[k] = 0; ed[k] = make_int2(0, 0);
    if (e < NE) {
      ed[k].x = src[e]; ed[k].y = dst[e];
      bin[k] = ed[k].y >> 8;
      rank[k] = atomicAdd(&hist[bin[k]], 1);
    }
  }
  __syncthreads();
  for (int i = tid; i < NBIN; i += 256) base[i] = atomicAdd(&gcnt[i], hist[i]);
  __syncthreads();
#pragma unroll
  for (int k = 0; k < 8; ++k) {
    int e = e0 + k * 256 + tid;
    if (e < NE) staging[bin[k] * BCAP + base[bin[k]] + rank[k]] = ed[k];
  }
}

// one block per bin; row starts rounded to EVEN so agg's int2 index loads are
// 8B-aligned.
__global__ __launch_bounds__(256) void bin_fill_kernel(const int2* __restrict__ staging,
                                                       const int* __restrict__ gcnt,
                                                       int* __restrict__ adj,
                                                       int* __restrict__ row_ptr,
                                                       int* __restrict__ cnt,
                                                       int* __restrict__ alloc) {
  __shared__ int hdeg[256], loc[256], c2[256];
  __shared__ int sbase;
  int b = blockIdx.x;
  int tid = threadIdx.x;
  hdeg[tid] = 0; c2[tid] = 0;
  __syncthreads();
  int n = gcnt[b];
  for (int i = tid; i < n; i += 256)
    atomicAdd(&hdeg[staging[b * BCAP + i].y & 255], 1);
  __syncthreads();
  int v = hdeg[tid];
  int va = (v + 1) & ~1;  // even-aligned allocation
  loc[tid] = va;
  __syncthreads();
  for (int off = 1; off < 256; off <<= 1) {
    int t = (tid >= off) ? loc[tid - off] : 0;
    __syncthreads();
    loc[tid] += t;
    __syncthreads();
  }
  if (tid == 255) sbase = atomicAdd(alloc, loc[255]);
  __syncthreads();
  int excl = loc[tid] - va;
  int node = b * 256 + tid;
  if (node < NN) { row_ptr[node] = sbase + excl; cnt[node] = v; }
  loc[tid] = excl;
  __syncthreads();
  for (int i = tid; i < n; i += 256) {
    int2 e = staging[b * BCAP + i];
    int local = e.y & 255;
    int r = atomicAdd(&c2[local], 1);
    adj[sbase + loc[local] + r] = e.x;
  }
}

// ---------------- prep: weight transposes + v2/s2 + out init + counters ----------------

struct WPtrs { const float* w[6]; const float* b_out; const float* b2_last;
               const float* w_out; };

__global__ __launch_bounds__(256) void prep_kernel(WPtrs ptrs, unsigned short* __restrict__ wt,
                                                   float* __restrict__ out,
                                                   int* __restrict__ gcnt,
                                                   int* __restrict__ alloc,
                                                   float* __restrict__ v2,
                                                   float* __restrict__ s2) {
  int i = blockIdx.x * 256 + threadIdx.x;  // 6*16384 elems, m uniform per block
  int m = i >> 14;
  int idx = i & 16383;
  int c = idx >> 7, k = idx & 127;
  wt[m * 16384 + idx] = f2b(ptrs.w[m][k * DIMH + c]);
  if (i < NGRAPH) out[i] = ptrs.b_out[0];
  if (i < NBIN) gcnt[i] = 0;
  if (i == NBIN) *alloc = 0;
  if (i < DIMH) {  // v2[k] = sum_c W2_l2[k][c] * w_out[256+c]  (4-way ILP)
    const float* w2r = ptrs.w[5] + i * DIMH;
    const float* wo = ptrs.w_out + 2 * DIMH;
    float s0 = 0.f, s1 = 0.f, sa = 0.f, sb = 0.f;
#pragma unroll 4
    for (int cc = 0; cc < DIMH; cc += 4) {
      s0 += w2r[cc] * wo[cc];
      s1 += w2r[cc + 1] * wo[cc + 1];
      sa += w2r[cc + 2] * wo[cc + 2];
      sb += w2r[cc + 3] * wo[cc + 3];
    }
    v2[i] = (s0 + s1) + (sa + sb);
  }
  if (i == DIMH) {  // s2 = dot(b2_l2, w_out[256:])
    const float* wo = ptrs.w_out + 2 * DIMH;
    float s0 = 0.f, s1 = 0.f, sa = 0.f, sb = 0.f;
#pragma unroll 4
    for (int cc = 0; cc < DIMH; cc += 4) {
      s0 += ptrs.b2_last[cc] * wo[cc];
      s1 += ptrs.b2_last[cc + 1] * wo[cc + 1];
      sa += ptrs.b2_last[cc + 2] * wo[cc + 2];
      sb += ptrs.b2_last[cc + 3] * wo[cc + 3];
    }
    *s2 = (s0 + s1) + (sa + sb);
  }
}

// h (row-major fp32) -> sliced bf16 [slice][node][16f]
__global__ void convh_kernel(const float* __restrict__ h, uint2* __restrict__ Hs) {
  int t = blockIdx.x * 256 + threadIdx.x;  // NN*32 groups of 4 feats
  if (t >= NN * 32) return;
  int node = t >> 5;
  int q = t & 31;            // feat group: feats q*4..q*4+3
  float4 v = *(const float4*)&h[node * DIMH + q * 4];
  uint2 o;
  o.x = pk2(v.x, v.y);
  o.y = pk2(v.z, v.w);
  Hs[(q >> 2) * (SL_U4 * 2) + node * 4 + (q & 3)] = o;
}

// ---------------- aggregation: sliced, XCD-affine, deep-ILP ----------------
__global__ __launch_bounds__(256) void agg_kernel(const uint4* __restrict__ Hs,
                                                  const int* __restrict__ row_ptr,
                                                  const int* __restrict__ cnt,
                                                  const int* __restrict__ adj,
                                                  uint4* __restrict__ Zs) {
  int bid = blockIdx.x;
  int slice = bid & 7;
  int nb = bid >> 3;
  int tid = threadIdx.x;
  int node = nb * 128 + (tid >> 1);
  int l2 = tid & 1;
  if (node >= NN) return;
  const uint4* hp = Hs + slice * SL_U4;
  int start = row_ptr[node];
  int c = cnt[node];
  float a[8];
  {
    uint4 own = hp[node * 2 + l2];
    a[0] = b2f_lo(own.x); a[1] = b2f_hi(own.x);
    a[2] = b2f_lo(own.y); a[3] = b2f_hi(own.y);
    a[4] = b2f_lo(own.z); a[5] = b2f_hi(own.z);
    a[6] = b2f_lo(own.w); a[7] = b2f_hi(own.w);
  }
  int j = 0;
  for (; j + 8 <= c; j += 8) {
    int2 i01 = *(const int2*)(adj + start + j);
    int2 i23 = *(const int2*)(adj + start + j + 2);
    int2 i45 = *(const int2*)(adj + start + j + 4);
    int2 i67 = *(const int2*)(adj + start + j + 6);
    uint4 u0 = hp[i01.x * 2 + l2];
    uint4 u1 = hp[i01.y * 2 + l2];
    uint4 u2 = hp[i23.x * 2 + l2];
    uint4 u3 = hp[i23.y * 2 + l2];
    uint4 u4 = hp[i45.x * 2 + l2];
    uint4 u5 = hp[i45.y * 2 + l2];
    uint4 u6 = hp[i67.x * 2 + l2];
    uint4 u7 = hp[i67.y * 2 + l2];
    add8(a, u0); add8(a, u1); add8(a, u2); add8(a, u3);
    add8(a, u4); add8(a, u5); add8(a, u6); add8(a, u7);
  }
  for (; j + 2 <= c; j += 2) {
    int2 i01 = *(const int2*)(adj + start + j);
    uint4 u0 = hp[i01.x * 2 + l2];
    uint4 u1 = hp[i01.y * 2 + l2];
    add8(a, u0); add8(a, u1);
  }
  if (j < c) {
    int n0 = adj[start + j];
    add8(a, hp[n0 * 2 + l2]);
  }
  uint4 o;
  o.x = pk2(a[0], a[1]);
  o.y = pk2(a[2], a[3]);
  o.z = pk2(a[4], a[5]);
  o.w = pk2(a[6], a[7]);
  Zs[slice * SL_U4 + node * 2 + l2] = o;
}

// ---------------- MLP mid-layer (l=0,1): round-9 structure, no runtime flags ----
// Wave-pair owns a tile stream (4 tiles); fb1+fb2 register-resident; Y1 through
// dbuf swizzled LDS; Y stored sliced + fused wout readout.
__global__ __launch_bounds__(256, 2) void mlp_mid_kernel(const unsigned short* __restrict__ X,
                                                         const unsigned short* __restrict__ W1t,
                                                         const float* __restrict__ b1,
                                                         const unsigned short* __restrict__ W2t,
                                                         const float* __restrict__ b2,
                                                         unsigned short* __restrict__ Y,
                                                         const int* __restrict__ gids,
                                                         const float* __restrict__ wout,
                                                         float* __restrict__ gout) {
  __shared__ unsigned short y1[2][2][2048];  // [pair][dbuf][16 rows x 128 cols bf16]
  __shared__ float s_gout[NGRAPH];
  int tid = threadIdx.x;
  if (tid < NGRAPH) s_gout[tid] = 0.f;

  int wv = tid >> 6;
  int lane = tid & 63;
  int pb = wv >> 1;
  int half = wv & 1;
  int l15 = lane & 15;
  int g = lane >> 4;
  int p = blockIdx.x * 2 + pb;

  // sliced A-load: feats kt*32+g*8..+7 of row R -> slice 2kt+(g>>1), half (g&1)
  int asl_base = (g >> 1) * SL_US + (g & 1) * 8 + l15 * 16;

  bf16x8 a[4];
  {
    int roff = p * 256;
#pragma unroll
    for (int kt = 0; kt < 4; ++kt)
      a[kt] = *(const bf16x8*)(X + 2 * kt * SL_US + roff + asl_base);
  }

  bf16x8 fb1[4][4], fb2[4][4];
  const unsigned short* w1b = W1t + (half * 64 + l15) * DIMH + g * 8;
  const unsigned short* w2b = W2t + (half * 64 + l15) * DIMH + g * 8;
#pragma unroll
  for (int n = 0; n < 4; ++n)
#pragma unroll
    for (int kt = 0; kt < 4; ++kt) {
      fb1[n][kt] = *(const bf16x8*)(w1b + n * 16 * DIMH + kt * 32);
      fb2[n][kt] = *(const bf16x8*)(w2b + n * 16 * DIMH + kt * 32);
    }
  float b1v[4], b2v[4], wov[4];
#pragma unroll
  for (int n = 0; n < 4; ++n) {
    int col = half * 64 + n * 16 + l15;
    b1v[n] = b1[col];
    b2v[n] = b2[col];
    wov[n] = wout[col];
  }
  __syncthreads();

#pragma unroll
  for (int i = 0; i < MLP_ITERS; ++i) {
    int rtc = p + i * PAIRS;
    bool active = rtc < NTILES;
    unsigned short* buf = y1[pb][i & 1];

    if (active) {
#pragma unroll
      for (int n = 0; n < 4; ++n) {
        f32x4 acc = (f32x4){0.f, 0.f, 0.f, 0.f};
#pragma unroll
        for (int kt = 0; kt < 4; ++kt)
          acc = __builtin_amdgcn_mfma_f32_16x16x32_bf16(a[kt], fb1[n][kt], acc, 0, 0, 0);
        int col2 = (half * 64 + n * 16 + l15) * 2;
#pragma unroll
        for (int r = 0; r < 4; ++r) {
          float f = fmaxf(acc[r] + b1v[n], 0.f);
          int row = 4 * g + r;
          buf[((row * 256 + col2) ^ (row << 4)) >> 1] = f2b(f);
        }
      }
    }

    // prefetch next tile's A fragments
    int rtn = p + (i + 1) * PAIRS;
    if (i + 1 < MLP_ITERS && rtn < NTILES) {
      int roff = rtn * 256;
#pragma unroll
      for (int kt = 0; kt < 4; ++kt)
        a[kt] = *(const bf16x8*)(X + 2 * kt * SL_US + roff + asl_base);
    }

    __syncthreads();  // Y1 tile complete (both halves)

    if (active) {
      bf16x8 a2[4];
#pragma unroll
      for (int kt = 0; kt < 4; ++kt)
        a2[kt] = *(const bf16x8*)&buf[((l15 * 256 + kt * 64 + g * 16) ^ (l15 << 4)) >> 1];

      float pr[4] = {0.f, 0.f, 0.f, 0.f};
#pragma unroll
      for (int n = 0; n < 4; ++n) {
        f32x4 acc = (f32x4){0.f, 0.f, 0.f, 0.f};
#pragma unroll
        for (int kt = 0; kt < 4; ++kt)
          acc = __builtin_amdgcn_mfma_f32_16x16x32_bf16(a2[kt], fb2[n][kt], acc, 0, 0, 0);
        int sl = 4 * half + n;  // output col slice
#pragma unroll
        for (int r = 0; r < 4; ++r) {
          float f = acc[r] + b2v[n];
          Y[sl * SL_US + (rtc * 16 + 4 * g + r) * 16 + l15] = f2b(f);
          pr[r] += f * wov[n];
        }
      }
#pragma unroll
      for (int r = 0; r < 4; ++r) {
#pragma unroll
        for (int off = 1; off < 16; off <<= 1) pr[r] += __shfl_xor(pr[r], off, 64);
      }
      if (l15 == 0) {
#pragma unroll
        for (int r = 0; r < 4; ++r)
          atomicAdd(&s_gout[gids[rtc * 16 + 4 * g + r]], pr[r]);
      }
    }
  }

  __syncthreads();
  if (tid < NGRAPH) {
    float v = s_gout[tid];
    if (v != 0.f) atomicAdd(&gout[tid], v);
  }
}

// ---------------- MLP last layer (l=2): GEMM1 + v2-dot only, no LDS exchange ----
// Wave handles 4 tiles of its 64-col half; fb1 register-resident; zero barriers
// in the loop. out[g] += dot(relu(z W1 + b1), v2) + s2 (s2 added by half 0).
__global__ __launch_bounds__(256, 2) void mlp_last_kernel(const unsigned short* __restrict__ X,
                                                          const unsigned short* __restrict__ W1t,
                                                          const float* __restrict__ b1,
                                                          const int* __restrict__ gids,
                                                          float* __restrict__ gout,
                                                          const float* __restrict__ v2,
                                                          const float* __restrict__ s2p) {
  __shared__ float s_gout[NGRAPH];
  int tid = threadIdx.x;
  if (tid < NGRAPH) s_gout[tid] = 0.f;

  int wv = tid >> 6;
  int lane = tid & 63;
  int half = wv & 1;          // col half
  int pbase = blockIdx.x * 2 + (wv >> 1);  // tile stream id in [0,1024)
  int l15 = lane & 15;
  int g = lane >> 4;

  int asl_base = (g >> 1) * SL_US + (g & 1) * 8 + l15 * 16;

  bf16x8 fb1[4][4];
  const unsigned short* w1b = W1t + (half * 64 + l15) * DIMH + g * 8;
#pragma unroll
  for (int n = 0; n < 4; ++n)
#pragma unroll
    for (int kt = 0; kt < 4; ++kt)
      fb1[n][kt] = *(const bf16x8*)(w1b + n * 16 * DIMH + kt * 32);
  float b1v[4], v2v[4];
#pragma unroll
  for (int n = 0; n < 4; ++n) {
    int col = half * 64 + n * 16 + l15;
    b1v[n] = b1[col];
    v2v[n] = v2[col];
  }
  float s2v = (half == 0) ? *s2p : 0.f;
  __syncthreads();  // s_gout zero visible

  bf16x8 a[4];
  {
    int roff = pbase * 256;
#pragma unroll
    for (int kt = 0; kt < 4; ++kt)
      a[kt] = *(const bf16x8*)(X + 2 * kt * SL_US + roff + asl_base);
  }

#pragma unroll
  for (int i = 0; i < MLP_ITERS; ++i) {
    int rtc = pbase + i * PAIRS;
    bool active = rtc < NTILES;

    bf16x8 cur[4];
#pragma unroll
    for (int kt = 0; kt < 4; ++kt) cur[kt] = a[kt];

    // prefetch next tile
    int rtn = pbase + (i + 1) * PAIRS;
    if (i + 1 < MLP_ITERS && rtn < NTILES) {
      int roff = rtn * 256;
#pragma unroll
      for (int kt = 0; kt < 4; ++kt)
        a[kt] = *(const bf16x8*)(X + 2 * kt * SL_US + roff + asl_base);
    }

    if (active) {
      float pr[4] = {0.f, 0.f, 0.f, 0.f};
#pragma unroll
      for (int n = 0; n < 4; ++n) {
        f32x4 acc = (f32x4){0.f, 0.f, 0.f, 0.f};
#pragma unroll
        for (int kt = 0; kt < 4; ++kt)
          acc = __builtin_amdgcn_mfma_f32_16x16x32_bf16(cur[kt], fb1[n][kt], acc, 0, 0, 0);
#pragma unroll
        for (int r = 0; r < 4; ++r)
          pr[r] += fmaxf(acc[r] + b1v[n], 0.f) * v2v[n];
      }
#pragma unroll
      for (int r = 0; r < 4; ++r) {
#pragma unroll
        for (int off = 1; off < 16; off <<= 1) pr[r] += __shfl_xor(pr[r], off, 64);
      }
      if (l15 == 0) {
#pragma unroll
        for (int r = 0; r < 4; ++r)
          atomicAdd(&s_gout[gids[rtc * 16 + 4 * g + r]], pr[r] + s2v);
      }
    }
  }

  __syncthreads();
  if (tid < NGRAPH) {
    float v = s_gout[tid];
    if (v != 0.f) atomicAdd(&gout[tid], v);
  }
}

// ---------------- launch ----------------

extern "C" void kernel_launch(void* const* d_in, const int* in_sizes, int n_in,
                              void* d_out, int out_size, void* d_ws, size_t ws_size,
                              hipStream_t stream) {
  const float* h = (const float*)d_in[0];
  const int* src = (const int*)d_in[1];
  const int* dst = (const int*)d_in[2];
  const int* gids = (const int*)d_in[3];
  const float* w_out = (const float*)d_in[16];
  const float* b_out = (const float*)d_in[17];
  float* out = (float*)d_out;

  char* base = (char*)d_ws;
  unsigned short* buf0 = (unsigned short*)(base);             // 12.8 MB (sliced io ping)
  unsigned short* buf1 = (unsigned short*)(base + 12800000);  // 12.8 MB (sliced io pong)
  int2* staging = (int2*)(base + 25600000);                   // 12,644,352 B
  int* adj = (int*)(base + 38400000);                         // 3,400,000 B (even-padded)
  int* row_ptr = (int*)(base + 41800064);                     // 200,000 B
  int* cnt = (int*)(base + 42000128);                         // 200,000 B
  int* gcnt = (int*)(base + 42200192);                        // 784 B
  int* alloc = (int*)(base + 42201024);                       // 4 B
  unsigned short* wt = (unsigned short*)(base + 42201088);    // 196,608 B
  float* v2 = (float*)(base + 42397696);                      // 512 B
  float* s2 = (float*)(base + 42398208);                      // 4 B
  unsigned short* Zs = (unsigned short*)(base + 42400000);    // 12.8 MB

  WPtrs ptrs;
  for (int l = 0; l < 3; ++l) {
    ptrs.w[2 * l] = (const float*)d_in[4 + l * 4];
    ptrs.w[2 * l + 1] = (const float*)d_in[6 + l * 4];
  }
  ptrs.b_out = b_out;
  ptrs.b2_last = (const float*)d_in[15];
  ptrs.w_out = w_out;

  prep_kernel<<<384, 256, 0, stream>>>(ptrs, wt, out, gcnt, alloc, v2, s2);
  bin_scatter_kernel<<<(NE + 2047) / 2048, 256, 0, stream>>>(src, dst, gcnt, staging);
  bin_fill_kernel<<<NBIN, 256, 0, stream>>>(staging, gcnt, adj, row_ptr, cnt, alloc);
  convh_kernel<<<(NN * 32 + 255) / 256, 256, 0, stream>>>(h, (uint2*)buf0);

  int agg_blocks = 391 * 8;  // ceil(50000/128) node-blocks x 8 slices (bid&7 = slice)

  for (int l = 0; l < 3; ++l) {
    const float* b1 = (const float*)d_in[5 + l * 4];
    const float* b2 = (const float*)d_in[7 + l * 4];
    const unsigned short* Hl = (l & 1) ? buf1 : buf0;
    unsigned short* Yl = (l & 1) ? buf0 : buf1;
    agg_kernel<<<agg_blocks, 256, 0, stream>>>((const uint4*)Hl, row_ptr, cnt, adj,
                                               (uint4*)Zs);
    if (l < 2) {
      mlp_mid_kernel<<<MLP_BLOCKS, 256, 0, stream>>>(Zs, wt + (2 * l) * 16384, b1,
                                                     wt + (2 * l + 1) * 16384, b2,
                                                     Yl, gids, w_out + l * DIMH, out);
    } else {
      mlp_last_kernel<<<MLP_BLOCKS, 256, 0, stream>>>(Zs, wt + (2 * l) * 16384, b1,
                                                      gids, out, v2, s2);
    }
  }
}